// Round 6
// baseline (560.860 us; speedup 1.0000x reference)
//
#include <hip/hip_runtime.h>
#include <stdint.h>

#define B 8192
#define T 512
#define K 24
#define BK (B * K)   // 196608

// Fused add + exact first-index argmax over 24 (value = aw[i] as float + tcj[i]).
// Tournament merges pair lower-index range (left) vs higher (right), keeping
// left on ties (strict > for right) => identical to jnp.argmax.
__device__ __forceinline__ void col_argmax(const int aw[K], const float tcj[K],
                                           float& mOut, int& pOut) {
    float cw[6]; int ci[6];
#pragma unroll
    for (int c = 0; c < 6; ++c) {
        float s0 = __int_as_float(aw[4*c+0]) + tcj[4*c+0];
        float s1 = __int_as_float(aw[4*c+1]) + tcj[4*c+1];
        float s2 = __int_as_float(aw[4*c+2]) + tcj[4*c+2];
        float s3 = __int_as_float(aw[4*c+3]) + tcj[4*c+3];
        bool ga = s1 > s0; float wa = ga ? s1 : s0; int ia = ga ? 4*c+1 : 4*c;
        bool gb = s3 > s2; float wb = gb ? s3 : s2; int ib = gb ? 4*c+3 : 4*c+2;
        bool gc = wb > wa;
        cw[c] = gc ? wb : wa; ci[c] = gc ? ib : ia;
    }
    bool h0 = cw[1] > cw[0]; float x0 = h0 ? cw[1] : cw[0]; int y0 = h0 ? ci[1] : ci[0];
    bool h1 = cw[3] > cw[2]; float x1 = h1 ? cw[3] : cw[2]; int y1 = h1 ? ci[3] : ci[2];
    bool h2 = cw[5] > cw[4]; float x2 = h2 ? cw[5] : cw[4]; int y2 = h2 ? ci[5] : ci[4];
    bool h3 = x1 > x0; float z = h3 ? x1 : x0; int v = h3 ? y1 : y0;
    bool h4 = x2 > z;
    mOut = h4 ? x2 : z; pOut = h4 ? y2 : v;
}

// First-index argmax of raw values (for the final alpha row).
__device__ __forceinline__ int argmax24_vals(const int aw[K]) {
    float cw[6]; int ci[6];
#pragma unroll
    for (int c = 0; c < 6; ++c) {
        float s0 = __int_as_float(aw[4*c+0]);
        float s1 = __int_as_float(aw[4*c+1]);
        float s2 = __int_as_float(aw[4*c+2]);
        float s3 = __int_as_float(aw[4*c+3]);
        bool ga = s1 > s0; float wa = ga ? s1 : s0; int ia = ga ? 4*c+1 : 4*c;
        bool gb = s3 > s2; float wb = gb ? s3 : s2; int ib = gb ? 4*c+3 : 4*c+2;
        bool gc = wb > wa;
        cw[c] = gc ? wb : wa; ci[c] = gc ? ib : ia;
    }
    bool h0 = cw[1] > cw[0]; float x0 = h0 ? cw[1] : cw[0]; int y0 = h0 ? ci[1] : ci[0];
    bool h1 = cw[3] > cw[2]; float x1 = h1 ? cw[3] : cw[2]; int y1 = h1 ? ci[3] : ci[2];
    bool h2 = cw[5] > cw[4]; float x2 = h2 ? cw[5] : cw[4]; int y2 = h2 ? ci[5] : ci[4];
    bool h3 = x1 > x0; int v = h3 ? y1 : y0; float z = h3 ? x1 : x0;
    bool h4 = x2 > z;
    return h4 ? y2 : v;
}

// ---------------------------------------------------------------------------
// Forward Viterbi, ZERO-LDS. 64-thread block = one wave = 8 batches (8 lanes
// x 3 rows/cols each). Alpha exchange via ds_bpermute_b32 straight from
// registers (24 pulls from 8 precomputed lane addresses) -> gathered slots are
// in ABSOLUTE row order, so the static tournament tie-break stays exact.
// No __shared__, no barriers, no write->read LDS round trip.
// WS=true: bp -> bp_ws[t][b][j] (t-major), last_tag -> tag_ws[b][T-1].
// WS=false: bp -> out[b][t] bytes 72..95, last_tag -> out[b][0] word 18.
// ---------------------------------------------------------------------------
template<bool WS>
__global__ __launch_bounds__(64) __attribute__((amdgpu_waves_per_eu(1, 1)))
void crf_forward(const float* __restrict__ inp,    // [B, T, K]
                 const float* __restrict__ trans,  // [K, K] (prev i -> cur j)
                 float* __restrict__ out,
                 uint8_t* __restrict__ bp_ws,      // [T, B, K]
                 uint8_t* __restrict__ tag_ws)     // [B, T]
{
    const int lane = threadIdx.x;          // one wave per block
    const int g    = lane >> 3;            // batch group 0..7
    const int l    = lane & 7;             // lane within group
    const int c0   = 3 * l;                // this lane's rows/cols c0..c0+2
    const int b    = blockIdx.x * 8 + g;   // 1024 blocks * 8 = 8192

    // bpermute byte-addresses of the 8 lanes in this group (lane index * 4)
    int adk[8];
#pragma unroll
    for (int k = 0; k < 8; ++k) adk[k] = ((lane & ~7) + k) << 2;

    float tc[3][K];                        // 72 regs; waves_per_eu(1,1) budget
#pragma unroll
    for (int j = 0; j < 3; ++j)
#pragma unroll
        for (int i = 0; i < K; ++i) tc[j][i] = trans[i * K + c0 + j];

    const float* ebl = inp + (size_t)b * T * K + c0;
    uint32_t*    obw = (uint32_t*)out + (size_t)b * T * K;

    uint8_t* bpp;
    size_t   bstride;
    if (WS) { bpp = bp_ws + (size_t)BK + (size_t)b * K + c0; bstride = BK; }
    else    { bpp = (uint8_t*)(obw + K + 18) + c0;           bstride = K * 4; }

    // t = 0: this lane's own three alpha rows live in registers
    float n0 = ebl[0], n1 = ebl[1], n2 = ebl[2];

    float e0 = ebl[K],     e1 = ebl[K + 1],     e2 = ebl[K + 2];      // e(1)
    float f0 = ebl[2 * K], f1 = ebl[2 * K + 1], f2 = ebl[2 * K + 2];  // e(2)

    int aw[K];

// Gather all 24 alpha rows of this group from registers via bpermute.
#define GATHER() do {                                                         \
    int n0i_ = __float_as_int(n0);                                            \
    int n1i_ = __float_as_int(n1);                                            \
    int n2i_ = __float_as_int(n2);                                            \
    _Pragma("unroll")                                                         \
    for (int k = 0; k < 8; ++k) {                                             \
        aw[3*k+0] = __builtin_amdgcn_ds_bpermute(adk[k], n0i_);               \
        aw[3*k+1] = __builtin_amdgcn_ds_bpermute(adk[k], n1i_);               \
        aw[3*k+2] = __builtin_amdgcn_ds_bpermute(adk[k], n2i_);               \
    }                                                                         \
} while (0)

// One Viterbi step: gather alpha, fused add+tournament per column, update
// own rows, store 3 bp bytes, advance bp pointer.
#define STEP(E0, E1, E2) do {                                                 \
    GATHER();                                                                 \
    float m0_, m1_, m2_; int p0_, p1_, p2_;                                   \
    col_argmax(aw, tc[0], m0_, p0_);                                          \
    col_argmax(aw, tc[1], m1_, p1_);                                          \
    col_argmax(aw, tc[2], m2_, p2_);                                          \
    n0 = m0_ + (E0); n1 = m1_ + (E1); n2 = m2_ + (E2);                        \
    bpp[0] = (uint8_t)p0_; bpp[1] = (uint8_t)p1_; bpp[2] = (uint8_t)p2_;      \
    bpp += bstride;                                                           \
} while (0)

#pragma unroll 1
    for (int it = 0; it < 255; ++it) {
        const int t = 1 + 2 * it;               // 1,3,...,509
        const float* pa = ebl + (size_t)(t + 2) * K;   // e(t+2), always valid
        float g0 = pa[0], g1 = pa[1], g2 = pa[2];
        STEP(e0, e1, e2);                       // step t
        int tb = t + 3; tb = tb > 511 ? 511 : tb;
        const float* pb = ebl + (size_t)tb * K;
        float h0 = pb[0], h1 = pb[1], h2 = pb[2];
        STEP(f0, f1, f2);                       // step t+1
        e0 = g0; e1 = g1; e2 = g2;
        f0 = h0; f1 = h1; f2 = h2;
    }
    STEP(e0, e1, e2);                           // t = 511 (final)
#undef STEP

    // last_tag = first-index argmax of alpha_{T-1}
    GATHER();
#undef GATHER
    if (l == 0) {
        int p = argmax24_vals(aw);
        if (WS) tag_ws[(size_t)b * T + (T - 1)] = (uint8_t)p;
        else    obw[18] = (uint32_t)p;
    }
}

// ---------------------------------------------------------------------------
// Chase (WS path): bp is [T][B][K] -> per step a wave reads 64 consecutive
// batches' 24B rows (1536B contiguous, coalesced) and addresses are
// chain-independent. 16-deep prefetch pipeline (~3.1 MB in flight chip-wide).
// ---------------------------------------------------------------------------
__global__ __launch_bounds__(64) __attribute__((amdgpu_waves_per_eu(1, 1)))
void crf_chase_t(const uint8_t* __restrict__ bp,   // [T, B, K]
                 uint8_t* __restrict__ tag)        // [B, T]
{
    const int b = blockIdx.x * 64 + threadIdx.x;
    uint8_t* tg = tag + (size_t)b * T;
    int cur = (int)tg[T - 1];
    const uint8_t* rowb = bp + (size_t)b * K;

    uint2 q[16][3];

#define CLOAD(S, U) do { int u_ = (U); u_ = u_ < 1 ? 1 : u_;                  \
    const uint2* r_ = (const uint2*)(rowb + (size_t)u_ * BK);                 \
    q[S][0] = r_[0]; q[S][1] = r_[1]; q[S][2] = r_[2]; } while (0)

#define CONS(S, U) do { int u_ = (U);                                         \
    if (u_ >= 1) {                                                            \
        tg[u_] = (uint8_t)cur;                                                \
        int ix_ = cur >> 2;                                                   \
        uint32_t wa_ = (ix_ & 1) ? q[S][0].y : q[S][0].x;                     \
        uint32_t wb_ = (ix_ & 1) ? q[S][1].y : q[S][1].x;                     \
        uint32_t wc_ = (ix_ & 1) ? q[S][2].y : q[S][2].x;                     \
        uint32_t w1_ = (ix_ & 2) ? wb_ : wa_;                                 \
        uint32_t w2_ = (ix_ & 4) ? wc_ : w1_;                                 \
        cur = (int)((w2_ >> ((cur & 3) * 8)) & 0xFF);                         \
    } else if (u_ == 0) { tg[0] = (uint8_t)cur; } } while (0)

#pragma unroll
    for (int s = 0; s < 16; ++s) CLOAD(s, 511 - s);

#pragma unroll 1
    for (int k2 = 0; k2 < 32; ++k2) {
        const int u0 = 511 - 16 * k2;
#pragma unroll
        for (int s = 0; s < 16; ++s) {
            CONS(s, u0 - s);
            CLOAD(s, u0 - s - 16);
        }
    }
#undef CLOAD
#undef CONS
}

// ---------------------------------------------------------------------------
// Fallback chase (bp embedded in out) — round-2 proven version.
// ---------------------------------------------------------------------------
__global__ __launch_bounds__(64) __attribute__((amdgpu_waves_per_eu(1, 1)))
void crf_chase_f(float* __restrict__ out)
{
    const int b = blockIdx.x * 64 + threadIdx.x;
    uint32_t* obw = (uint32_t*)out + (size_t)b * T * K;

    uint32_t w[4][8][6];

#define LOADG(GG, SLOT) do {                                                  \
    int gg_ = (GG);                                                           \
    if (gg_ < 64) {                                                           \
      _Pragma("unroll")                                                       \
      for (int q_ = 0; q_ < 8; ++q_) {                                        \
        int u_ = 511 - 8 * gg_ - q_;                                          \
        const uint32_t* r_ = obw + (size_t)u_ * K + 18;                       \
        *(uint2*)&w[SLOT][q_][0] = *(const uint2*)(r_);                       \
        *(uint2*)&w[SLOT][q_][2] = *(const uint2*)(r_ + 2);                   \
        *(uint2*)&w[SLOT][q_][4] = *(const uint2*)(r_ + 4);                   \
      }                                                                       \
    }                                                                         \
  } while (0)

#define PROCG(GG, SLOT) do {                                                  \
    int gg_ = (GG);                                                           \
    _Pragma("unroll")                                                         \
    for (int q_ = 0; q_ < 8; ++q_) {                                          \
      int u_ = 511 - 8 * gg_ - q_;                                            \
      if (u_ > 0) {                                                           \
        int idx_ = cur >> 2;                                                  \
        uint32_t wA_ = (idx_ & 1) ? w[SLOT][q_][1] : w[SLOT][q_][0];          \
        uint32_t wB_ = (idx_ & 1) ? w[SLOT][q_][3] : w[SLOT][q_][2];          \
        uint32_t wC_ = (idx_ & 1) ? w[SLOT][q_][5] : w[SLOT][q_][4];          \
        uint32_t wAB_ = (idx_ & 2) ? wB_ : wA_;                               \
        uint32_t wd_  = (idx_ & 4) ? wC_ : wAB_;                              \
        int nxt_ = (int)((wd_ >> ((cur & 3) * 8)) & 0xFF);                    \
        obw[(size_t)u_ * K + 18] = (uint32_t)cur;                             \
        cur = nxt_;                                                           \
      } else {                                                                \
        obw[18] = (uint32_t)cur;                                              \
      }                                                                       \
    }                                                                         \
  } while (0)

    int cur = (int)obw[18];

    LOADG(0, 0); LOADG(1, 1); LOADG(2, 2); LOADG(3, 3);

#pragma unroll 1
    for (int base = 0; base < 60; base += 4) {
        PROCG(base + 0, 0); LOADG(base + 4, 0);
        PROCG(base + 1, 1); LOADG(base + 5, 1);
        PROCG(base + 2, 2); LOADG(base + 6, 2);
        PROCG(base + 3, 3); LOADG(base + 7, 3);
    }
    PROCG(60, 0); PROCG(61, 1); PROCG(62, 2); PROCG(63, 3);
#undef LOADG
#undef PROCG
}

// ---------------------------------------------------------------------------
// One-hot scatter: one thread per (b,t), 6 x b128 stores per record.
// ---------------------------------------------------------------------------
template<bool WS>
__global__ __launch_bounds__(256) void crf_onehot(
    float* __restrict__ out, const uint8_t* __restrict__ tag_ws)
{
    const size_t idx = (size_t)blockIdx.x * 256 + threadIdx.x;  // < B*T
    uint32_t* rec = (uint32_t*)out + idx * K;
    int tag;
    if (WS) tag = (int)tag_ws[idx];
    else    tag = (int)rec[18];
#pragma unroll
    for (int c = 0; c < 6; ++c) {
        uint4 v;
        v.x = (tag == 4*c+0) ? 0x3F800000u : 0u;
        v.y = (tag == 4*c+1) ? 0x3F800000u : 0u;
        v.z = (tag == 4*c+2) ? 0x3F800000u : 0u;
        v.w = (tag == 4*c+3) ? 0x3F800000u : 0u;
        *(uint4*)(rec + 4*c) = v;
    }
}

extern "C" void kernel_launch(void* const* d_in, const int* in_sizes, int n_in,
                              void* d_out, int out_size, void* d_ws, size_t ws_size,
                              hipStream_t stream) {
    const float* inp   = (const float*)d_in[0];   // [8192, 512, 24]
    const float* trans = (const float*)d_in[1];   // [24, 24]
    float*       out   = (float*)d_out;           // [8192, 512, 24]

    const size_t need = (size_t)B * T * K + (size_t)B * T;  // bp + tags
    if (ws_size >= need) {
        uint8_t* bp = (uint8_t*)d_ws;                       // [T][B][K]
        uint8_t* tg = (uint8_t*)d_ws + (size_t)B * T * K;   // [B][T]
        crf_forward<true><<<B / 8, 64, 0, stream>>>(inp, trans, out, bp, tg);
        crf_chase_t<<<B / 64, 64, 0, stream>>>(bp, tg);
        crf_onehot<true><<<(B * T) / 256, 256, 0, stream>>>(out, tg);
    } else {
        crf_forward<false><<<B / 8, 64, 0, stream>>>(inp, trans, out, nullptr, nullptr);
        crf_chase_f<<<B / 64, 64, 0, stream>>>(out);
        crf_onehot<false><<<(B * T) / 256, 256, 0, stream>>>(out, nullptr);
    }
}